// Round 3
// baseline (243.076 us; speedup 1.0000x reference)
//
#include <hip/hip_runtime.h>
#include <hip/hip_bf16.h>
#include <cstdint>

// ---------------------------------------------------------------------------
// SingleHeadAttentionLayer: B=4, S=2048, D=KD=VD=1024, fp32 in/out.
// Round 11: T3-minimum 2-phase double-buffered gemm_core. Old core was
// 1-phase (stage -> sync -> compute -> sync): full HBM/L2 load latency on
// the critical path each K-step, hidden only by 2 co-resident blocks.
// New core: prefetch K-step kk+1 into buf^1 while computing buf[cur]; ONE
// __syncthreads() per iteration (its implicit vmcnt(0)+lgkmcnt(0) drain is
// the correctness fence). WAR-safe: stage targets the buffer the barrier
// guarantees all waves finished reading. LDS 32->64 KB = 2 blocks/CU (what
// occupancy already was). Guide: T3 recipe, m248v2 (+10% same-probe),
// m230 (2ph 682 TF vs 1ph ~540 at this tile).
// Pipeline (round-10 algebra kept):
//   prep2:  Wo cast, Wq^T/Wk^T/Wv^T casts, bvo, c, zero lsum   (2818 blk)
//   gemmA:  Mt(64) + Wvo(64) + m1(16) + m2(16) + x cast(8192)  (8352 blk)
//   gemmB1: y2 = x@Mt^T + m2 (512) + u = x@m1 + c (128)        (640 blk)
//   gemmB2: Ut = (x@Wvo^T + bvo)^T (512) + P=exp(|..|/32)      (1056 blk)
//   pvo:    out = (P@U)/l + bo                                 (512 blk)
// ---------------------------------------------------------------------------

#define BM 128

typedef __attribute__((ext_vector_type(8))) __bf16 bf16x8;
typedef __attribute__((ext_vector_type(4))) __bf16 bf16x4;
typedef __attribute__((ext_vector_type(4))) float floatx4;

struct Ptr3 { const float* p[3]; };

__device__ __forceinline__ void async_copy16(const __bf16* g, const __bf16* l) {
  __builtin_amdgcn_global_load_lds(
      (const __attribute__((address_space(1))) unsigned int*)(const void*)g,
      (__attribute__((address_space(3))) unsigned int*)(unsigned)(uintptr_t)(const void*)l,
      16, 0, 0);
}

// 128x128 tile; K consumed 64/iter as two 32-panels (verified lane-linear
// global_load_lds layout). 2-phase double-buffered: stage kk+1 while
// computing kk. Iterates [kBeg, kEnd).
// MUST be called from exactly ONE call site per kernel (single 64 KB LDS).
__device__ __forceinline__ void gemm_core(const __bf16* __restrict__ pA,
                                          const __bf16* __restrict__ pB,
                                          int K, int kBeg, int kEnd, int mb,
                                          int nb, floatx4 (&acc)[4][4]) {
  // [buf][panel][BM*32] -- 8 KB per panel, 64 KB total
  __shared__ __align__(16) __bf16 As[2][2][BM * 32];
  __shared__ __align__(16) __bf16 Bs[2][2][BM * 32];

  const int t = threadIdx.x;
  const int lane = t & 63;
  const int wave = t >> 6;
  const int quad = lane >> 4;
  const int l16 = lane & 15;
  const int wm = wave >> 1;
  const int wn = wave & 1;

  const __bf16* gA = pA + (long)(mb * BM + (t >> 2)) * K + ((t & 3) * 8);
  const __bf16* gB = pB + (long)(nb * BM + (t >> 2)) * K + ((t & 3) * 8);
  const long rowHalf = (long)64 * K;

  // stage K-step kk (two 32-wide panels of A and B) into buffer `buf`
  auto stage = [&](int kk, int buf) {
    const long ko = (long)kk * 64;
    __bf16* lA0 = &As[buf][0][t * 8];
    __bf16* lA1 = &As[buf][1][t * 8];
    __bf16* lB0 = &Bs[buf][0][t * 8];
    __bf16* lB1 = &Bs[buf][1][t * 8];
    async_copy16(gA + ko, lA0);
    async_copy16(gA + ko + rowHalf, lA0 + 2048);
    async_copy16(gA + ko + 32, lA1);
    async_copy16(gA + ko + 32 + rowHalf, lA1 + 2048);
    async_copy16(gB + ko, lB0);
    async_copy16(gB + ko + rowHalf, lB0 + 2048);
    async_copy16(gB + ko + 32, lB1);
    async_copy16(gB + ko + 32 + rowHalf, lB1 + 2048);
  };

  stage(kBeg, 0);
  __syncthreads();  // implicit vmcnt(0): first tile landed

  for (int kk = kBeg; kk < kEnd; ++kk) {
    const int cur = (kk - kBeg) & 1;
    if (kk + 1 < kEnd) stage(kk + 1, cur ^ 1);  // overlap with compute below

#pragma unroll
    for (int p = 0; p < 2; ++p) {
      const __bf16* Asp = &As[cur][p][0];
      const __bf16* Bsp = &Bs[cur][p][0];
      bf16x8 af[4], bfr[4];
#pragma unroll
      for (int i = 0; i < 4; ++i) {
        af[i] = *(const bf16x8*)&Asp[(wm * 64 + i * 16 + l16) * 32 + quad * 8];
        bfr[i] = *(const bf16x8*)&Bsp[(wn * 64 + i * 16 + l16) * 32 + quad * 8];
      }
#pragma unroll
      for (int i = 0; i < 4; ++i)
#pragma unroll
        for (int j = 0; j < 4; ++j)
          acc[i][j] = __builtin_amdgcn_mfma_f32_16x16x32_bf16(af[i], bfr[j],
                                                              acc[i][j], 0, 0, 0);
    }
    // Single barrier: implicit vmcnt(0) (prefetch landed) + lgkmcnt(0)
    // (our ds_reads done) + s_barrier (everyone done reading buf[cur],
    // so next iter may stage into it).
    __syncthreads();
  }
}

// ---------------- prep2: weight-side preparation ----------------------------
// [0,1024): Wo cast | [1024,1792): Wq^T,Wk^T,Wv^T transpose-casts (256 each)
// [1792,2816): bvo[d] = sum_v bv[v]*Wo[d][v] | 2816: c = bq.bk | 2817: lsum=0
__global__ void prep2(const float* __restrict__ Wo, Ptr3 tp,
                      const float* __restrict__ bv, const float* __restrict__ bq,
                      const float* __restrict__ bk,
                      __bf16* __restrict__ Wob, __bf16* __restrict__ Wqt,
                      __bf16* __restrict__ Wkt, __bf16* __restrict__ Wvt,
                      float* __restrict__ bvo, float* __restrict__ cscal,
                      float* __restrict__ lsum) {
  __shared__ __bf16 tile[64][66];
  __shared__ float wsum[4];
  const int bid = blockIdx.x;
  const int t = threadIdx.x;
  if (bid < 1024) {  // Wo cast
    const long e = ((long)bid * 256 + t) * 4;
    const float4 f = *(const float4*)(Wo + e);
    bf16x4 o;
    o[0] = (__bf16)f.x; o[1] = (__bf16)f.y; o[2] = (__bf16)f.z; o[3] = (__bf16)f.w;
    *(bf16x4*)(Wob + e) = o;
  } else if (bid < 1792) {  // transposed casts: Wqt, Wkt, Wvt
    const int seg = (bid - 1024) >> 8;   // 0:Wq 1:Wk 2:Wv
    const int idx = (bid - 1024) & 255;
    const float* src = tp.p[seg];
    __bf16* dstw = seg == 0 ? Wqt : (seg == 1 ? Wkt : Wvt);
    const int r0 = (idx >> 4) * 64, c0 = (idx & 15) * 64;
#pragma unroll
    for (int e = 0; e < 16; ++e) {
      const int i = e * 256 + t;
      const int r = i >> 6, c = i & 63;
      tile[r][c] = (__bf16)src[(long)(r0 + r) * 1024 + (c0 + c)];
    }
    __syncthreads();
#pragma unroll
    for (int e = 0; e < 16; ++e) {
      const int i = e * 256 + t;
      const int r = i >> 6, c = i & 63;
      dstw[(long)(c0 + r) * 1024 + (r0 + c)] = tile[c][r];
    }
  } else if (bid < 2816) {  // bvo
    const int d = bid - 1792;
    const float* row = Wo + (long)d * 1024;
    float s = 0.f;
    for (int v = t; v < 1024; v += 256) s += bv[v] * row[v];
#pragma unroll
    for (int off = 32; off > 0; off >>= 1) s += __shfl_down(s, off, 64);
    if ((t & 63) == 0) wsum[t >> 6] = s;
    __syncthreads();
    if (t == 0) bvo[d] = wsum[0] + wsum[1] + wsum[2] + wsum[3];
  } else if (bid == 2816) {  // c = bq . bk
    float s = 0.f;
    for (int i = t; i < 1024; i += 256) s += bq[i] * bk[i];
#pragma unroll
    for (int off = 32; off > 0; off >>= 1) s += __shfl_down(s, off, 64);
    if ((t & 63) == 0) wsum[t >> 6] = s;
    __syncthreads();
    if (t == 0) *cscal = wsum[0] + wsum[1] + wsum[2] + wsum[3];
  } else {  // zero lsum (8192 floats)
#pragma unroll
    for (int e = 0; e < 8; ++e)
      *(float4*)(lsum + (e * 256 + t) * 4) = float4{0.f, 0.f, 0.f, 0.f};
  }
}

// ---------------- gemmA: Mt(64) + Wvo(64) + m1(16) + m2(16) + x cast(8192) --
__global__ void __launch_bounds__(256, 2)
gemmA(const __bf16* __restrict__ Wkt, const __bf16* __restrict__ Wqt,
      const __bf16* __restrict__ Wob, const __bf16* __restrict__ Wvt,
      __bf16* __restrict__ Mt, __bf16* __restrict__ Wvo,
      const float* __restrict__ bk, const float* __restrict__ bq,
      float* __restrict__ m1f, float* __restrict__ m2f,
      const float* __restrict__ x, __bf16* __restrict__ xb) {
  const int id = blockIdx.x;
  const int t = threadIdx.x;

  if (id >= 160) {  // x cast
    const long i = ((long)(id - 160) * 256 + t) * 4;
    const float4 f = *(const float4*)(x + i);
    bf16x4 o;
    o[0] = (__bf16)f.x; o[1] = (__bf16)f.y; o[2] = (__bf16)f.z; o[3] = (__bf16)f.w;
    *(bf16x4*)(xb + i) = o;
    return;
  }
  if (id >= 128) {  // m1[d] = Wqt[d,:].bk  /  m2[e] = Wkt[e,:].bq
    const int q = (id - 128) & 15;
    const bool isM2 = (id - 128) >= 16;
    const __bf16* Wt = isM2 ? Wkt : Wqt;
    const float* bvec = isM2 ? bq : bk;
    float* dst = isM2 ? m2f : m1f;
    const int lane = t & 63, wave = t >> 6, qd = lane >> 4, l16 = lane & 15;
#pragma unroll
    for (int rr = 0; rr < 4; ++rr) {
      const int row = q * 64 + (wave * 4 + qd) * 4 + rr;
      const __bf16* wr = Wt + (long)row * 1024 + l16 * 64;
      const float* bp = bvec + l16 * 64;
      float s = 0.f;
#pragma unroll
      for (int jj = 0; jj < 8; ++jj) {
        bf16x8 wv = *(const bf16x8*)(wr + jj * 8);
#pragma unroll
        for (int e = 0; e < 8; ++e) s += (float)wv[e] * bp[jj * 8 + e];
      }
      s += __shfl_xor(s, 1, 64);
      s += __shfl_xor(s, 2, 64);
      s += __shfl_xor(s, 4, 64);
      s += __shfl_xor(s, 8, 64);
      if (l16 == 0) dst[row] = s;
    }
    return;
  }

  // GEMM blocks: [0,64): Mt = Wkt @ Wqt contraction; [64,128): Wvo = Wo@Wv
  const __bf16 *pA, *pB;
  __bf16* dst;
  int mb, nb;
  if (id < 64) {
    mb = id >> 3; nb = id & 7;
    pA = Wkt; pB = Wqt; dst = Mt;
  } else {
    const int w = id - 64;
    mb = w >> 3; nb = w & 7;
    pA = Wob; pB = Wvt; dst = Wvo;
  }

  floatx4 acc[4][4] = {};
  gemm_core(pA, pB, 1024, 0, 16, mb, nb, acc);

  const int lane = t & 63, wave = t >> 6;
  const int rb = (wave >> 1) * 64 + (lane >> 4) * 4;
  const int cb = (wave & 1) * 64 + (lane & 15);
#pragma unroll
  for (int j4 = 0; j4 < 4; ++j4) {
    const int gc = nb * 128 + cb + j4 * 16;
#pragma unroll
    for (int i = 0; i < 4; ++i) {
      const int gr = mb * BM + rb + i * 16;
#pragma unroll
      for (int r = 0; r < 4; ++r)
        dst[(long)(gr + r) * 1024 + gc] = (__bf16)acc[i][j4][r];
    }
  }
}

// ---------------- gemmB1: y2 = x@Mt^T + m2 (512) + u = x.m1 + c (128) -------
__global__ void __launch_bounds__(256, 2)
gemmB1(const __bf16* __restrict__ xb, const __bf16* __restrict__ Mt,
       const float* __restrict__ m2f, __bf16* __restrict__ y2,
       const float* __restrict__ m1f, const float* __restrict__ cscal,
       float* __restrict__ uvec) {
  const int id = blockIdx.x;
  const int t = threadIdx.x;

  if (id >= 512) {  // u rows
    const int k = id - 512;
    const int lane = t & 63, wave = t >> 6, qd = lane >> 4, l16 = lane & 15;
    const float c = *cscal;
#pragma unroll
    for (int rr = 0; rr < 4; ++rr) {
      const int row = k * 64 + (wave * 4 + qd) * 4 + rr;  // 0..8191
      const __bf16* xr = xb + (long)row * 1024 + l16 * 64;
      const float* mp = m1f + l16 * 64;
      float s = 0.f;
#pragma unroll
      for (int jj = 0; jj < 8; ++jj) {
        bf16x8 xv = *(const bf16x8*)(xr + jj * 8);
#pragma unroll
        for (int e = 0; e < 8; ++e) s += (float)xv[e] * mp[jj * 8 + e];
      }
      s += __shfl_xor(s, 1, 64);
      s += __shfl_xor(s, 2, 64);
      s += __shfl_xor(s, 4, 64);
      s += __shfl_xor(s, 8, 64);
      if (l16 == 0) uvec[row] = s + c;
    }
    return;
  }

  // y2 GEMM, XCD-swizzled
  const int xcd = id & 7;
  const int j = id >> 3;          // 64 per XCD
  const int mb = xcd * 8 + (j & 7);  // 0..63 (8192 rows)
  const int nb = j >> 3;             // 0..7

  floatx4 acc[4][4] = {};
  gemm_core(xb, Mt, 1024, 0, 16, mb, nb, acc);

  const int lane = t & 63, wave = t >> 6;
  const int rb = (wave >> 1) * 64 + (lane >> 4) * 4;
  const int cb = (wave & 1) * 64 + (lane & 15);
#pragma unroll
  for (int j4 = 0; j4 < 4; ++j4) {
    const int gc = nb * 128 + cb + j4 * 16;
    const float bvv = m2f[gc];
#pragma unroll
    for (int i = 0; i < 4; ++i) {
      const int gr = mb * BM + rb + i * 16;
#pragma unroll
      for (int r = 0; r < 4; ++r)
        y2[(long)(gr + r) * 1024 + gc] = (__bf16)(acc[i][j4][r] + bvv);
    }
  }
}

// ---------------- gemmB2: Ut (512) + scores (544) ---------------------------
__global__ void __launch_bounds__(256, 2)
gemmB2(const __bf16* __restrict__ xb, const __bf16* __restrict__ Wvo,
       const float* __restrict__ bvo, __bf16* __restrict__ Ut,
       const __bf16* __restrict__ y2, const float* __restrict__ uvec,
       __bf16* __restrict__ P, float* __restrict__ lsum,
       int S, int KD, int D) {
  const int id = blockIdx.x;
  const __bf16 *pA, *pB;
  int mb, nb, b, mode;
  if (id < 512) {  // Ut = (x @ Wvo^T + bvo)^T
    const int xcd = id & 7;
    const int j = id >> 3;        // 64 per XCD
    mb = xcd * 8 + (j & 7);
    nb = j >> 3;
    b = 0;
    mode = 0;
    pA = xb;
    pB = Wvo;
  } else {  // scores, exact-packed: 17 uniform tiles per (XCD, batch)
    const int sid = id - 512;
    const int xcd = sid & 7;
    const int r = sid >> 3;       // 0..67
    b = r / 17;
    const int ci = r - b * 17;    // 0..16
    const int n1 = xcd + 1;       // tiles for mb = xcd
    mb = (ci < n1) ? xcd : (15 - xcd);
    nb = (ci < n1) ? ci : (ci - n1);
    mode = 1;
    pA = y2 + (long)b * S * KD;
    pB = xb + (long)b * S * KD;
  }

  floatx4 acc[4][4] = {};
  gemm_core(pA, pB, KD, 0, KD / 64, mb, nb, acc);

  const int t = threadIdx.x;
  const int lane = t & 63, wave = t >> 6;
  const int l16 = lane & 15;
  const int rb = (wave >> 1) * 64 + (lane >> 4) * 4;
  const int cb = (wave & 1) * 64 + l16;

  if (mode == 0) {
    // Ut[bb][dout][s] = U[bb][s][dout]; BM=128 rows lie in one batch
    const int bb = (mb * BM) / S;
    const int s0 = mb * BM - bb * S;
#pragma unroll
    for (int j4 = 0; j4 < 4; ++j4) {
      const int gc = nb * 128 + cb + j4 * 16;
      const float bv = bvo[gc];
#pragma unroll
      for (int i = 0; i < 4; ++i) {
        const int sr = s0 + rb + i * 16;
        bf16x4 o;
#pragma unroll
        for (int r = 0; r < 4; ++r) o[r] = (__bf16)(acc[i][j4][r] + bv);
        *(bf16x4*)&Ut[((long)bb * D + gc) * S + sr] = o;
      }
    }
  } else {
    __bf16* C = P + (long)b * S * S;
    float* lrow = lsum + (long)b * S;
    const float sc = 0.03125f;  // 1/sqrt(1024)
#pragma unroll
    for (int i = 0; i < 4; ++i) {
#pragma unroll
      for (int r = 0; r < 4; ++r) {
        const int row = mb * BM + rb + i * 16 + r;
        const float urow = uvec[(long)b * S + row];
        float psum = 0.f;
#pragma unroll
        for (int j4 = 0; j4 < 4; ++j4) {
          const int col = nb * 128 + cb + j4 * 16;
          const float p =
              (col <= row) ? __expf(fabsf(acc[i][j4][r] + urow) * sc) : 0.f;
          psum += p;
          C[(long)row * S + col] = (__bf16)p;
        }
        // 16 lanes of this quad share `row`: butterfly then one atomic
        psum += __shfl_xor(psum, 1, 64);
        psum += __shfl_xor(psum, 2, 64);
        psum += __shfl_xor(psum, 4, 64);
        psum += __shfl_xor(psum, 8, 64);
        if (l16 == 0) atomicAdd(&lrow[row], psum);
      }
    }
  }
}

// ---------------- pvo: out = (P @ U)/l + bo, fp32 ---------------------------
// 512 blocks; per XCD x: first 32 blocks mb=15-x (heavy, 32-2x kSteps), next
// 32 mb=x (light, 2x+2) -> round-robin CU fill pairs heavy+light = 34/CU.
__global__ void __launch_bounds__(256, 2)
gemm_pvo(const __bf16* __restrict__ P, const __bf16* __restrict__ Ut,
         const float* __restrict__ lsum, const float* __restrict__ bo,
         float* __restrict__ out, int S, int D) {
  const int id = blockIdx.x;
  const int xcd = id & 7;
  const int j = id >> 3;          // 0..63
  const int half = j >> 5;        // 0: heavy, 1: light
  const int idx = j & 31;
  const int b = idx >> 3;
  const int nb = idx & 7;
  const int mb = half ? xcd : (15 - xcd);

  floatx4 acc[4][4] = {};
  gemm_core(P + (long)b * S * S, Ut + (long)b * D * S, S, 0, 2 * (mb + 1), mb,
            nb, acc);

  const int t = threadIdx.x;
  const int lane = t & 63, wave = t >> 6;
  const int rb = (wave >> 1) * 64 + (lane >> 4) * 4;
  const int cb = (wave & 1) * 64 + (lane & 15);
  const float* lrow = lsum + (long)b * S;

#pragma unroll
  for (int i = 0; i < 4; ++i) {
#pragma unroll
    for (int r = 0; r < 4; ++r) {
      const int row = mb * BM + rb + i * 16 + r;
      const float inv = 1.f / lrow[row];
#pragma unroll
      for (int j4 = 0; j4 < 4; ++j4) {
        const int col = nb * 128 + cb + j4 * 16;
        out[((long)b * S + row) * D + col] = acc[i][j4][r] * inv + bo[col];
      }
    }
  }
}

extern "C" void kernel_launch(void* const* d_in, const int* in_sizes, int n_in,
                              void* d_out, int out_size, void* d_ws, size_t ws_size,
                              hipStream_t stream) {
  const float* x = (const float*)d_in[0];
  const float* Wq = (const float*)d_in[1];
  const float* bq = (const float*)d_in[2];
  const float* Wk = (const float*)d_in[3];
  const float* bk = (const float*)d_in[4];
  const float* Wv = (const float*)d_in[5];
  const float* bv = (const float*)d_in[6];
  const float* Wo = (const float*)d_in[7];
  const float* bo = (const float*)d_in[8];
  float* out = (float*)d_out;

  constexpr int B = 4, S = 2048, D = 1024, KD = 1024;
  constexpr long MB_ = 1024 * 1024;

  char* w = (char*)d_ws;
  __bf16* xb  = (__bf16*)(w);              // 16 MB
  __bf16* y2  = (__bf16*)(w + 16 * MB_);   // 16 MB
  __bf16* Ut  = (__bf16*)(w + 32 * MB_);   // 16 MB
  __bf16* P   = (__bf16*)(w + 48 * MB_);   // 32 MB
  __bf16* Wob = (__bf16*)(w + 80 * MB_);   // 2 MB
  __bf16* Wqt = (__bf16*)(w + 82 * MB_);   // 2 MB
  __bf16* Wkt = (__bf16*)(w + 84 * MB_);   // 2 MB
  __bf16* Wvt = (__bf16*)(w + 86 * MB_);   // 2 MB
  __bf16* Mt  = (__bf16*)(w + 88 * MB_);   // 2 MB
  __bf16* Wvo = (__bf16*)(w + 90 * MB_);   // 2 MB
  float* lsum  = (float*)(w + 92 * MB_);             // 32 KB
  float* uvec  = (float*)(w + 92 * MB_ + 32768);     // 32 KB
  float* bvo   = (float*)(w + 92 * MB_ + 65536);     // 4 KB
  float* m2f   = (float*)(w + 92 * MB_ + 69632);     // 4 KB
  float* m1f   = (float*)(w + 92 * MB_ + 73728);     // 4 KB
  float* cscal = (float*)(w + 92 * MB_ + 77824);     // 4 B

  Ptr3 tp{{Wq, Wk, Wv}};
  prep2<<<2818, 256, 0, stream>>>(Wo, tp, bv, bq, bk, Wob, Wqt, Wkt, Wvt,
                                  bvo, cscal, lsum);

  gemmA<<<8352, 256, 0, stream>>>(Wkt, Wqt, Wob, Wvt, Mt, Wvo, bk, bq,
                                  m1f, m2f, x, xb);

  gemmB1<<<640, 256, 0, stream>>>(xb, Mt, m2f, y2, m1f, cscal, uvec);

  gemmB2<<<1056, 256, 0, stream>>>(xb, Wvo, bvo, Ut, y2, uvec, P, lsum, S, KD, D);

  gemm_pvo<<<512, 256, 0, stream>>>(P, Ut, lsum, bo, out, S, D);
}

// Round 4
// 236.970 us; speedup vs baseline: 1.0258x; 1.0258x over previous
//
#include <hip/hip_runtime.h>
#include <hip/hip_bf16.h>
#include <cstdint>

// ---------------------------------------------------------------------------
// SingleHeadAttentionLayer: B=4, S=2048, D=KD=VD=1024, fp32 in/out.
// Round 12: 3-buffer ring gemm_core (T3+T4): K-step 32, counted
// s_waitcnt vmcnt(4) + ONE raw s_barrier per iteration, loads stay 2 tiles
// deep in flight across barriers (never drained to 0 in the loop).
// Plus rule-#21 LDS bank-conflict swizzle: global SOURCE col-chunk XOR
// ((t>>3)&3), linear LDS dest (global_load_lds requirement), read-side
// qsw = quad ^ ((l16>>1)&3)  -> 16-lane pass hits 2 lanes/bank-group
// (structural minimum; was 8-way -> measured 2x LDS penalty, 4.3M cycles).
// LDS 48 KB -> 3 blocks/CU (was 64 KB / 2 in R11).
// Race ledger: tile kk's 4 loads oldest at iter-kk vmcnt(4); raw barrier
// after per-wave wait => full tile visible; stage target buf[(cur+2)%3]
// last read iter kk-1 (before this barrier); clamped dup-prefetch keeps
// vmcnt count uniform; sched_barrier(0) pins code motion (rule #18).
// Pipeline (round-10 algebra):
//   prep2:  Wo cast, Wq^T/Wk^T/Wv^T casts, bvo, c, zero lsum   (2818 blk)
//   gemmA:  Mt(64) + Wvo(64) + m1(16) + m2(16) + x cast(8192)  (8352 blk)
//   gemmB1: y2 = x@Mt^T + m2 (512) + u = x@m1 + c (128)        (640 blk)
//   gemmB2: Ut = (x@Wvo^T + bvo)^T (512) + P=exp(|..|/32)      (1056 blk)
//   pvo:    out = (P@U)/l + bo                                 (512 blk)
// ---------------------------------------------------------------------------

#define BM 128

typedef __attribute__((ext_vector_type(8))) __bf16 bf16x8;
typedef __attribute__((ext_vector_type(4))) __bf16 bf16x4;
typedef __attribute__((ext_vector_type(4))) float floatx4;

struct Ptr3 { const float* p[3]; };

__device__ __forceinline__ void async_copy16(const __bf16* g, const __bf16* l) {
  __builtin_amdgcn_global_load_lds(
      (const __attribute__((address_space(1))) unsigned int*)(const void*)g,
      (__attribute__((address_space(3))) unsigned int*)(unsigned)(uintptr_t)(const void*)l,
      16, 0, 0);
}

// 128x128 tile; K consumed 32/iter; 3-buffer ring with 2 tiles in flight.
// Iterates [kBeg, kEnd) in K32 units. Single call site per kernel (48 KB LDS).
__device__ __forceinline__ void gemm_core(const __bf16* __restrict__ pA,
                                          const __bf16* __restrict__ pB,
                                          int K, int kBeg, int kEnd, int mb,
                                          int nb, floatx4 (&acc)[4][4]) {
  __shared__ __align__(16) __bf16 As[3][BM * 32];
  __shared__ __align__(16) __bf16 Bs[3][BM * 32];

  const int t = threadIdx.x;
  const int lane = t & 63;
  const int wave = t >> 6;
  const int quad = lane >> 4;
  const int l16 = lane & 15;
  const int wm = wave >> 1;
  const int wn = wave & 1;
  // read-side swizzle (matches source-side inverse swizzle below)
  const int qsw = quad ^ ((l16 >> 1) & 3);

  // Source inverse-swizzle: LDS slot t holds global (row=t>>2,
  // colchunk=(t&3)^((t>>3)&3)). Read at (row,q') returns colchunk
  // q'^((row>>1)&3); (row>>1)&3 == (t>>3)&3 for both 64-row halves.
  const int srow = t >> 2;
  const int scol = ((t & 3) ^ ((t >> 3) & 3)) * 8;
  const __bf16* gA = pA + (long)(mb * BM + srow) * K + scol;
  const __bf16* gB = pB + (long)(nb * BM + srow) * K + scol;
  const long rowHalf = (long)64 * K;

  // stage one K32 tile (4 loads/thread: A lo/hi, B lo/hi) into buffer `buf`
  auto stage = [&](int kk, int buf) {
    const long ko = (long)kk * 32;
    __bf16* lA = &As[buf][t * 8];
    __bf16* lB = &Bs[buf][t * 8];
    async_copy16(gA + ko, lA);
    async_copy16(gA + ko + rowHalf, lA + 2048);
    async_copy16(gB + ko, lB);
    async_copy16(gB + ko + rowHalf, lB + 2048);
  };

  stage(kBeg, 0);
  stage(kBeg + 1 < kEnd ? kBeg + 1 : kEnd - 1, 1);

  for (int kk = kBeg; kk < kEnd; ++kk) {
    const int cur = (kk - kBeg) % 3;
    // Wait own oldest 4 loads (tile kk) -- tiles kk+1 stay in flight.
    asm volatile("s_waitcnt vmcnt(4)" ::: "memory");
    __builtin_amdgcn_s_barrier();          // raw: no vmcnt drain
    __builtin_amdgcn_sched_barrier(0);     // pin: nothing moves across
    {
      const int nxt = kk + 2;
      stage(nxt < kEnd ? nxt : kEnd - 1, (cur + 2) % 3);
    }
    const __bf16* Asp = &As[cur][0];
    const __bf16* Bsp = &Bs[cur][0];
    bf16x8 af[4], bfr[4];
#pragma unroll
    for (int i = 0; i < 4; ++i) {
      af[i] = *(const bf16x8*)&Asp[(wm * 64 + i * 16 + l16) * 32 + qsw * 8];
      bfr[i] = *(const bf16x8*)&Bsp[(wn * 64 + i * 16 + l16) * 32 + qsw * 8];
    }
#pragma unroll
    for (int i = 0; i < 4; ++i)
#pragma unroll
      for (int j = 0; j < 4; ++j)
        acc[i][j] = __builtin_amdgcn_mfma_f32_16x16x32_bf16(af[i], bfr[j],
                                                            acc[i][j], 0, 0, 0);
  }
  __syncthreads();  // drain leftover dup-prefetches before epilogue
}

// ---------------- prep2: weight-side preparation ----------------------------
// [0,1024): Wo cast | [1024,1792): Wq^T,Wk^T,Wv^T transpose-casts (256 each)
// [1792,2816): bvo[d] = sum_v bv[v]*Wo[d][v] | 2816: c = bq.bk | 2817: lsum=0
__global__ void prep2(const float* __restrict__ Wo, Ptr3 tp,
                      const float* __restrict__ bv, const float* __restrict__ bq,
                      const float* __restrict__ bk,
                      __bf16* __restrict__ Wob, __bf16* __restrict__ Wqt,
                      __bf16* __restrict__ Wkt, __bf16* __restrict__ Wvt,
                      float* __restrict__ bvo, float* __restrict__ cscal,
                      float* __restrict__ lsum) {
  __shared__ __bf16 tile[64][66];
  __shared__ float wsum[4];
  const int bid = blockIdx.x;
  const int t = threadIdx.x;
  if (bid < 1024) {  // Wo cast
    const long e = ((long)bid * 256 + t) * 4;
    const float4 f = *(const float4*)(Wo + e);
    bf16x4 o;
    o[0] = (__bf16)f.x; o[1] = (__bf16)f.y; o[2] = (__bf16)f.z; o[3] = (__bf16)f.w;
    *(bf16x4*)(Wob + e) = o;
  } else if (bid < 1792) {  // transposed casts: Wqt, Wkt, Wvt
    const int seg = (bid - 1024) >> 8;   // 0:Wq 1:Wk 2:Wv
    const int idx = (bid - 1024) & 255;
    const float* src = tp.p[seg];
    __bf16* dstw = seg == 0 ? Wqt : (seg == 1 ? Wkt : Wvt);
    const int r0 = (idx >> 4) * 64, c0 = (idx & 15) * 64;
#pragma unroll
    for (int e = 0; e < 16; ++e) {
      const int i = e * 256 + t;
      const int r = i >> 6, c = i & 63;
      tile[r][c] = (__bf16)src[(long)(r0 + r) * 1024 + (c0 + c)];
    }
    __syncthreads();
#pragma unroll
    for (int e = 0; e < 16; ++e) {
      const int i = e * 256 + t;
      const int r = i >> 6, c = i & 63;
      dstw[(long)(c0 + r) * 1024 + (r0 + c)] = tile[c][r];
    }
  } else if (bid < 2816) {  // bvo
    const int d = bid - 1792;
    const float* row = Wo + (long)d * 1024;
    float s = 0.f;
    for (int v = t; v < 1024; v += 256) s += bv[v] * row[v];
#pragma unroll
    for (int off = 32; off > 0; off >>= 1) s += __shfl_down(s, off, 64);
    if ((t & 63) == 0) wsum[t >> 6] = s;
    __syncthreads();
    if (t == 0) bvo[d] = wsum[0] + wsum[1] + wsum[2] + wsum[3];
  } else if (bid == 2816) {  // c = bq . bk
    float s = 0.f;
    for (int i = t; i < 1024; i += 256) s += bq[i] * bk[i];
#pragma unroll
    for (int off = 32; off > 0; off >>= 1) s += __shfl_down(s, off, 64);
    if ((t & 63) == 0) wsum[t >> 6] = s;
    __syncthreads();
    if (t == 0) *cscal = wsum[0] + wsum[1] + wsum[2] + wsum[3];
  } else {  // zero lsum (8192 floats)
#pragma unroll
    for (int e = 0; e < 8; ++e)
      *(float4*)(lsum + (e * 256 + t) * 4) = float4{0.f, 0.f, 0.f, 0.f};
  }
}

// ---------------- gemmA: Mt(64) + Wvo(64) + m1(16) + m2(16) + x cast(8192) --
__global__ void __launch_bounds__(256, 3)
gemmA(const __bf16* __restrict__ Wkt, const __bf16* __restrict__ Wqt,
      const __bf16* __restrict__ Wob, const __bf16* __restrict__ Wvt,
      __bf16* __restrict__ Mt, __bf16* __restrict__ Wvo,
      const float* __restrict__ bk, const float* __restrict__ bq,
      float* __restrict__ m1f, float* __restrict__ m2f,
      const float* __restrict__ x, __bf16* __restrict__ xb) {
  const int id = blockIdx.x;
  const int t = threadIdx.x;

  if (id >= 160) {  // x cast
    const long i = ((long)(id - 160) * 256 + t) * 4;
    const float4 f = *(const float4*)(x + i);
    bf16x4 o;
    o[0] = (__bf16)f.x; o[1] = (__bf16)f.y; o[2] = (__bf16)f.z; o[3] = (__bf16)f.w;
    *(bf16x4*)(xb + i) = o;
    return;
  }
  if (id >= 128) {  // m1[d] = Wqt[d,:].bk  /  m2[e] = Wkt[e,:].bq
    const int q = (id - 128) & 15;
    const bool isM2 = (id - 128) >= 16;
    const __bf16* Wt = isM2 ? Wkt : Wqt;
    const float* bvec = isM2 ? bq : bk;
    float* dst = isM2 ? m2f : m1f;
    const int lane = t & 63, wave = t >> 6, qd = lane >> 4, l16 = lane & 15;
#pragma unroll
    for (int rr = 0; rr < 4; ++rr) {
      const int row = q * 64 + (wave * 4 + qd) * 4 + rr;
      const __bf16* wr = Wt + (long)row * 1024 + l16 * 64;
      const float* bp = bvec + l16 * 64;
      float s = 0.f;
#pragma unroll
      for (int jj = 0; jj < 8; ++jj) {
        bf16x8 wv = *(const bf16x8*)(wr + jj * 8);
#pragma unroll
        for (int e = 0; e < 8; ++e) s += (float)wv[e] * bp[jj * 8 + e];
      }
      s += __shfl_xor(s, 1, 64);
      s += __shfl_xor(s, 2, 64);
      s += __shfl_xor(s, 4, 64);
      s += __shfl_xor(s, 8, 64);
      if (l16 == 0) dst[row] = s;
    }
    return;
  }

  // GEMM blocks: [0,64): Mt = Wkt @ Wqt contraction; [64,128): Wvo = Wo@Wv
  const __bf16 *pA, *pB;
  __bf16* dst;
  int mb, nb;
  if (id < 64) {
    mb = id >> 3; nb = id & 7;
    pA = Wkt; pB = Wqt; dst = Mt;
  } else {
    const int w = id - 64;
    mb = w >> 3; nb = w & 7;
    pA = Wob; pB = Wvt; dst = Wvo;
  }

  floatx4 acc[4][4] = {};
  gemm_core(pA, pB, 1024, 0, 32, mb, nb, acc);

  const int lane = t & 63, wave = t >> 6;
  const int rb = (wave >> 1) * 64 + (lane >> 4) * 4;
  const int cb = (wave & 1) * 64 + (lane & 15);
#pragma unroll
  for (int j4 = 0; j4 < 4; ++j4) {
    const int gc = nb * 128 + cb + j4 * 16;
#pragma unroll
    for (int i = 0; i < 4; ++i) {
      const int gr = mb * BM + rb + i * 16;
#pragma unroll
      for (int r = 0; r < 4; ++r)
        dst[(long)(gr + r) * 1024 + gc] = (__bf16)acc[i][j4][r];
    }
  }
}

// ---------------- gemmB1: y2 = x@Mt^T + m2 (512) + u = x.m1 + c (128) -------
__global__ void __launch_bounds__(256, 3)
gemmB1(const __bf16* __restrict__ xb, const __bf16* __restrict__ Mt,
       const float* __restrict__ m2f, __bf16* __restrict__ y2,
       const float* __restrict__ m1f, const float* __restrict__ cscal,
       float* __restrict__ uvec) {
  const int id = blockIdx.x;
  const int t = threadIdx.x;

  if (id >= 512) {  // u rows
    const int k = id - 512;
    const int lane = t & 63, wave = t >> 6, qd = lane >> 4, l16 = lane & 15;
    const float c = *cscal;
#pragma unroll
    for (int rr = 0; rr < 4; ++rr) {
      const int row = k * 64 + (wave * 4 + qd) * 4 + rr;  // 0..8191
      const __bf16* xr = xb + (long)row * 1024 + l16 * 64;
      const float* mp = m1f + l16 * 64;
      float s = 0.f;
#pragma unroll
      for (int jj = 0; jj < 8; ++jj) {
        bf16x8 xv = *(const bf16x8*)(xr + jj * 8);
#pragma unroll
        for (int e = 0; e < 8; ++e) s += (float)xv[e] * mp[jj * 8 + e];
      }
      s += __shfl_xor(s, 1, 64);
      s += __shfl_xor(s, 2, 64);
      s += __shfl_xor(s, 4, 64);
      s += __shfl_xor(s, 8, 64);
      if (l16 == 0) uvec[row] = s + c;
    }
    return;
  }

  // y2 GEMM, XCD-swizzled
  const int xcd = id & 7;
  const int j = id >> 3;          // 64 per XCD
  const int mb = xcd * 8 + (j & 7);  // 0..63 (8192 rows)
  const int nb = j >> 3;             // 0..7

  floatx4 acc[4][4] = {};
  gemm_core(xb, Mt, 1024, 0, 32, mb, nb, acc);

  const int lane = t & 63, wave = t >> 6;
  const int rb = (wave >> 1) * 64 + (lane >> 4) * 4;
  const int cb = (wave & 1) * 64 + (lane & 15);
#pragma unroll
  for (int j4 = 0; j4 < 4; ++j4) {
    const int gc = nb * 128 + cb + j4 * 16;
    const float bvv = m2f[gc];
#pragma unroll
    for (int i = 0; i < 4; ++i) {
      const int gr = mb * BM + rb + i * 16;
#pragma unroll
      for (int r = 0; r < 4; ++r)
        y2[(long)(gr + r) * 1024 + gc] = (__bf16)(acc[i][j4][r] + bvv);
    }
  }
}

// ---------------- gemmB2: Ut (512) + scores (544) ---------------------------
__global__ void __launch_bounds__(256, 3)
gemmB2(const __bf16* __restrict__ xb, const __bf16* __restrict__ Wvo,
       const float* __restrict__ bvo, __bf16* __restrict__ Ut,
       const __bf16* __restrict__ y2, const float* __restrict__ uvec,
       __bf16* __restrict__ P, float* __restrict__ lsum,
       int S, int KD, int D) {
  const int id = blockIdx.x;
  const __bf16 *pA, *pB;
  int mb, nb, b, mode;
  if (id < 512) {  // Ut = (x @ Wvo^T + bvo)^T
    const int xcd = id & 7;
    const int j = id >> 3;        // 64 per XCD
    mb = xcd * 8 + (j & 7);
    nb = j >> 3;
    b = 0;
    mode = 0;
    pA = xb;
    pB = Wvo;
  } else {  // scores, exact-packed: 17 uniform tiles per (XCD, batch)
    const int sid = id - 512;
    const int xcd = sid & 7;
    const int r = sid >> 3;       // 0..67
    b = r / 17;
    const int ci = r - b * 17;    // 0..16
    const int n1 = xcd + 1;       // tiles for mb = xcd
    mb = (ci < n1) ? xcd : (15 - xcd);
    nb = (ci < n1) ? ci : (ci - n1);
    mode = 1;
    pA = y2 + (long)b * S * KD;
    pB = xb + (long)b * S * KD;
  }

  floatx4 acc[4][4] = {};
  gemm_core(pA, pB, KD, 0, KD / 32, mb, nb, acc);

  const int t = threadIdx.x;
  const int lane = t & 63, wave = t >> 6;
  const int l16 = lane & 15;
  const int rb = (wave >> 1) * 64 + (lane >> 4) * 4;
  const int cb = (wave & 1) * 64 + l16;

  if (mode == 0) {
    // Ut[bb][dout][s] = U[bb][s][dout]; BM=128 rows lie in one batch
    const int bb = (mb * BM) / S;
    const int s0 = mb * BM - bb * S;
#pragma unroll
    for (int j4 = 0; j4 < 4; ++j4) {
      const int gc = nb * 128 + cb + j4 * 16;
      const float bv = bvo[gc];
#pragma unroll
      for (int i = 0; i < 4; ++i) {
        const int sr = s0 + rb + i * 16;
        bf16x4 o;
#pragma unroll
        for (int r = 0; r < 4; ++r) o[r] = (__bf16)(acc[i][j4][r] + bv);
        *(bf16x4*)&Ut[((long)bb * D + gc) * S + sr] = o;
      }
    }
  } else {
    __bf16* C = P + (long)b * S * S;
    float* lrow = lsum + (long)b * S;
    const float sc = 0.03125f;  // 1/sqrt(1024)
#pragma unroll
    for (int i = 0; i < 4; ++i) {
#pragma unroll
      for (int r = 0; r < 4; ++r) {
        const int row = mb * BM + rb + i * 16 + r;
        const float urow = uvec[(long)b * S + row];
        float psum = 0.f;
#pragma unroll
        for (int j4 = 0; j4 < 4; ++j4) {
          const int col = nb * 128 + cb + j4 * 16;
          const float p =
              (col <= row) ? __expf(fabsf(acc[i][j4][r] + urow) * sc) : 0.f;
          psum += p;
          C[(long)row * S + col] = (__bf16)p;
        }
        // 16 lanes of this quad share `row`: butterfly then one atomic
        psum += __shfl_xor(psum, 1, 64);
        psum += __shfl_xor(psum, 2, 64);
        psum += __shfl_xor(psum, 4, 64);
        psum += __shfl_xor(psum, 8, 64);
        if (l16 == 0) atomicAdd(&lrow[row], psum);
      }
    }
  }
}

// ---------------- pvo: out = (P @ U)/l + bo, fp32 ---------------------------
// 512 blocks; per XCD x: first 32 blocks mb=15-x (heavy), next 32 mb=x
// (light) -> round-robin CU fill pairs heavy+light.
__global__ void __launch_bounds__(256, 3)
gemm_pvo(const __bf16* __restrict__ P, const __bf16* __restrict__ Ut,
         const float* __restrict__ lsum, const float* __restrict__ bo,
         float* __restrict__ out, int S, int D) {
  const int id = blockIdx.x;
  const int xcd = id & 7;
  const int j = id >> 3;          // 0..63
  const int half = j >> 5;        // 0: heavy, 1: light
  const int idx = j & 31;
  const int b = idx >> 3;
  const int nb = idx & 7;
  const int mb = half ? xcd : (15 - xcd);

  floatx4 acc[4][4] = {};
  gemm_core(P + (long)b * S * S, Ut + (long)b * D * S, S, 0, 4 * (mb + 1), mb,
            nb, acc);

  const int t = threadIdx.x;
  const int lane = t & 63, wave = t >> 6;
  const int rb = (wave >> 1) * 64 + (lane >> 4) * 4;
  const int cb = (wave & 1) * 64 + (lane & 15);
  const float* lrow = lsum + (long)b * S;

#pragma unroll
  for (int i = 0; i < 4; ++i) {
#pragma unroll
    for (int r = 0; r < 4; ++r) {
      const int row = mb * BM + rb + i * 16 + r;
      const float inv = 1.f / lrow[row];
#pragma unroll
      for (int j4 = 0; j4 < 4; ++j4) {
        const int col = nb * 128 + cb + j4 * 16;
        out[((long)b * S + row) * D + col] = acc[i][j4][r] * inv + bo[col];
      }
    }
  }
}

extern "C" void kernel_launch(void* const* d_in, const int* in_sizes, int n_in,
                              void* d_out, int out_size, void* d_ws, size_t ws_size,
                              hipStream_t stream) {
  const float* x = (const float*)d_in[0];
  const float* Wq = (const float*)d_in[1];
  const float* bq = (const float*)d_in[2];
  const float* Wk = (const float*)d_in[3];
  const float* bk = (const float*)d_in[4];
  const float* Wv = (const float*)d_in[5];
  const float* bv = (const float*)d_in[6];
  const float* Wo = (const float*)d_in[7];
  const float* bo = (const float*)d_in[8];
  float* out = (float*)d_out;

  constexpr int B = 4, S = 2048, D = 1024, KD = 1024;
  constexpr long MB_ = 1024 * 1024;

  char* w = (char*)d_ws;
  __bf16* xb  = (__bf16*)(w);              // 16 MB
  __bf16* y2  = (__bf16*)(w + 16 * MB_);   // 16 MB
  __bf16* Ut  = (__bf16*)(w + 32 * MB_);   // 16 MB
  __bf16* P   = (__bf16*)(w + 48 * MB_);   // 32 MB
  __bf16* Wob = (__bf16*)(w + 80 * MB_);   // 2 MB
  __bf16* Wqt = (__bf16*)(w + 82 * MB_);   // 2 MB
  __bf16* Wkt = (__bf16*)(w + 84 * MB_);   // 2 MB
  __bf16* Wvt = (__bf16*)(w + 86 * MB_);   // 2 MB
  __bf16* Mt  = (__bf16*)(w + 88 * MB_);   // 2 MB
  __bf16* Wvo = (__bf16*)(w + 90 * MB_);   // 2 MB
  float* lsum  = (float*)(w + 92 * MB_);             // 32 KB
  float* uvec  = (float*)(w + 92 * MB_ + 32768);     // 32 KB
  float* bvo   = (float*)(w + 92 * MB_ + 65536);     // 4 KB
  float* m2f   = (float*)(w + 92 * MB_ + 69632);     // 4 KB
  float* m1f   = (float*)(w + 92 * MB_ + 73728);     // 4 KB
  float* cscal = (float*)(w + 92 * MB_ + 77824);     // 4 B

  Ptr3 tp{{Wq, Wk, Wv}};
  prep2<<<2818, 256, 0, stream>>>(Wo, tp, bv, bq, bk, Wob, Wqt, Wkt, Wvt,
                                  bvo, cscal, lsum);

  gemmA<<<8352, 256, 0, stream>>>(Wkt, Wqt, Wob, Wvt, Mt, Wvo, bk, bq,
                                  m1f, m2f, x, xb);

  gemmB1<<<640, 256, 0, stream>>>(xb, Mt, m2f, y2, m1f, cscal, uvec);

  gemmB2<<<1056, 256, 0, stream>>>(xb, Wvo, bvo, Ut, y2, uvec, P, lsum, S, KD, D);

  gemm_pvo<<<512, 256, 0, stream>>>(P, Ut, lsum, bo, out, S, D);
}

// Round 5
// 232.486 us; speedup vs baseline: 1.0456x; 1.0193x over previous
//
#include <hip/hip_runtime.h>
#include <hip/hip_bf16.h>
#include <cstdint>

// ---------------------------------------------------------------------------
// SingleHeadAttentionLayer: B=4, S=2048, D=KD=VD=1024, fp32 in/out.
// Round 13: 256x256-tile ring core (gemm_core256) for the dense GEMMs.
// R4 post-mortem: 128^2 ring plateaus at ~540 TF; conflicts=0, counted
// vmcnt -- residue is barrier overhead at 16-MFMA/wave granularity (m233).
// Fix per guide ladder: bigger tile = more MFMA per barrier. gemm_core256
// keeps R4's EXACT verified sync ledger (4 loads/stage, vmcnt(4), 3-buf
// ring, raw s_barrier + sched_barrier(0), same XOR swizzle math) at 512
// threads / 8 waves x (128x64) / 96 KB LDS / 1 block/CU.
//   prep2:   weights prep (unchanged)
//   gemmA:   Mt + Wvo + m1/m2 + x cast (unchanged, 128^2 core)
//   big1:    y2 (128) + Ut (128) @256^2  [256 blocks = exact 1/CU]
//            + u = x@m1 + c (128 trailing GEMV blocks)
//   scoresK: P = exp(|y2.x^T+u|/32) causal + rowsums (544 blk, 128^2 core)
//   pvo:     out = (P@U)/l + bo (512 blk, 128^2 core, heavy-light pairs)
// ---------------------------------------------------------------------------

#define BM 128

typedef __attribute__((ext_vector_type(8))) __bf16 bf16x8;
typedef __attribute__((ext_vector_type(4))) __bf16 bf16x4;
typedef __attribute__((ext_vector_type(4))) float floatx4;

struct Ptr3 { const float* p[3]; };

__device__ __forceinline__ void async_copy16(const __bf16* g, const __bf16* l) {
  __builtin_amdgcn_global_load_lds(
      (const __attribute__((address_space(1))) unsigned int*)(const void*)g,
      (__attribute__((address_space(3))) unsigned int*)(unsigned)(uintptr_t)(const void*)l,
      16, 0, 0);
}

// ---------------- 128x128 ring core (R4, verified: conflicts=0) -------------
__device__ __forceinline__ void gemm_core(const __bf16* __restrict__ pA,
                                          const __bf16* __restrict__ pB,
                                          int K, int kBeg, int kEnd, int mb,
                                          int nb, floatx4 (&acc)[4][4]) {
  __shared__ __align__(16) __bf16 As[3][BM * 32];
  __shared__ __align__(16) __bf16 Bs[3][BM * 32];

  const int t = threadIdx.x;
  const int lane = t & 63;
  const int wave = t >> 6;
  const int quad = lane >> 4;
  const int l16 = lane & 15;
  const int wm = wave >> 1;
  const int wn = wave & 1;
  const int qsw = quad ^ ((l16 >> 1) & 3);

  const int srow = t >> 2;
  const int scol = ((t & 3) ^ ((t >> 3) & 3)) * 8;
  const __bf16* gA = pA + (long)(mb * BM + srow) * K + scol;
  const __bf16* gB = pB + (long)(nb * BM + srow) * K + scol;
  const long rowHalf = (long)64 * K;

  auto stage = [&](int kk, int buf) {
    const long ko = (long)kk * 32;
    __bf16* lA = &As[buf][t * 8];
    __bf16* lB = &Bs[buf][t * 8];
    async_copy16(gA + ko, lA);
    async_copy16(gA + ko + rowHalf, lA + 2048);
    async_copy16(gB + ko, lB);
    async_copy16(gB + ko + rowHalf, lB + 2048);
  };

  stage(kBeg, 0);
  stage(kBeg + 1 < kEnd ? kBeg + 1 : kEnd - 1, 1);

  for (int kk = kBeg; kk < kEnd; ++kk) {
    const int cur = (kk - kBeg) % 3;
    asm volatile("s_waitcnt vmcnt(4)" ::: "memory");
    __builtin_amdgcn_s_barrier();
    __builtin_amdgcn_sched_barrier(0);
    {
      const int nxt = kk + 2;
      stage(nxt < kEnd ? nxt : kEnd - 1, (cur + 2) % 3);
    }
    const __bf16* Asp = &As[cur][0];
    const __bf16* Bsp = &Bs[cur][0];
    bf16x8 af[4], bfr[4];
#pragma unroll
    for (int i = 0; i < 4; ++i) {
      af[i] = *(const bf16x8*)&Asp[(wm * 64 + i * 16 + l16) * 32 + qsw * 8];
      bfr[i] = *(const bf16x8*)&Bsp[(wn * 64 + i * 16 + l16) * 32 + qsw * 8];
    }
#pragma unroll
    for (int i = 0; i < 4; ++i)
#pragma unroll
      for (int j = 0; j < 4; ++j)
        acc[i][j] = __builtin_amdgcn_mfma_f32_16x16x32_bf16(af[i], bfr[j],
                                                            acc[i][j], 0, 0, 0);
  }
  __syncthreads();
}

// ---------------- 256x256 ring core: 512 thr, 8 waves x (128x64) ------------
// Same sync ledger as gemm_core: 4 async copies/stage, vmcnt(4), 3-buf ring.
// Swizzle identical (row stride 32 elem unchanged; (row>>1)&3 key invariant
// holds for both 128-row halves since 128>>1 = 64 == 0 mod 4).
__device__ __forceinline__ void gemm_core256(const __bf16* __restrict__ pA,
                                             const __bf16* __restrict__ pB,
                                             int K, int kBeg, int kEnd, int mb,
                                             int nb, floatx4 (&acc)[8][4]) {
  __shared__ __align__(16) __bf16 As[3][256 * 32];
  __shared__ __align__(16) __bf16 Bs[3][256 * 32];

  const int t = threadIdx.x;          // 0..511
  const int lane = t & 63;
  const int wave = t >> 6;            // 0..7
  const int quad = lane >> 4;
  const int l16 = lane & 15;
  const int wm = wave >> 2;           // 0..1 -> rows wm*128
  const int wn = wave & 3;            // 0..3 -> cols wn*64
  const int qsw = quad ^ ((l16 >> 1) & 3);

  const int srow = t >> 2;            // 0..127
  const int scol = ((t & 3) ^ ((t >> 3) & 3)) * 8;
  const __bf16* gA = pA + (long)(mb * 256 + srow) * K + scol;
  const __bf16* gB = pB + (long)(nb * 256 + srow) * K + scol;
  const long rowHalf = (long)128 * K;

  auto stage = [&](int kk, int buf) {
    const long ko = (long)kk * 32;
    __bf16* lA = &As[buf][t * 8];
    __bf16* lB = &Bs[buf][t * 8];
    async_copy16(gA + ko, lA);
    async_copy16(gA + ko + rowHalf, lA + 4096);
    async_copy16(gB + ko, lB);
    async_copy16(gB + ko + rowHalf, lB + 4096);
  };

  stage(kBeg, 0);
  stage(kBeg + 1 < kEnd ? kBeg + 1 : kEnd - 1, 1);

  for (int kk = kBeg; kk < kEnd; ++kk) {
    const int cur = (kk - kBeg) % 3;
    asm volatile("s_waitcnt vmcnt(4)" ::: "memory");
    __builtin_amdgcn_s_barrier();
    __builtin_amdgcn_sched_barrier(0);
    {
      const int nxt = kk + 2;
      stage(nxt < kEnd ? nxt : kEnd - 1, (cur + 2) % 3);
    }
    const __bf16* Asp = &As[cur][0];
    const __bf16* Bsp = &Bs[cur][0];
    bf16x8 af[8], bfr[4];
#pragma unroll
    for (int j = 0; j < 4; ++j)
      bfr[j] = *(const bf16x8*)&Bsp[(wn * 64 + j * 16 + l16) * 32 + qsw * 8];
#pragma unroll
    for (int i = 0; i < 8; ++i)
      af[i] = *(const bf16x8*)&Asp[(wm * 128 + i * 16 + l16) * 32 + qsw * 8];
#pragma unroll
    for (int i = 0; i < 8; ++i)
#pragma unroll
      for (int j = 0; j < 4; ++j)
        acc[i][j] = __builtin_amdgcn_mfma_f32_16x16x32_bf16(af[i], bfr[j],
                                                            acc[i][j], 0, 0, 0);
  }
  __syncthreads();
}

// ---------------- prep2: weight-side preparation ----------------------------
__global__ void prep2(const float* __restrict__ Wo, Ptr3 tp,
                      const float* __restrict__ bv, const float* __restrict__ bq,
                      const float* __restrict__ bk,
                      __bf16* __restrict__ Wob, __bf16* __restrict__ Wqt,
                      __bf16* __restrict__ Wkt, __bf16* __restrict__ Wvt,
                      float* __restrict__ bvo, float* __restrict__ cscal,
                      float* __restrict__ lsum) {
  __shared__ __bf16 tile[64][66];
  __shared__ float wsum[4];
  const int bid = blockIdx.x;
  const int t = threadIdx.x;
  if (bid < 1024) {  // Wo cast
    const long e = ((long)bid * 256 + t) * 4;
    const float4 f = *(const float4*)(Wo + e);
    bf16x4 o;
    o[0] = (__bf16)f.x; o[1] = (__bf16)f.y; o[2] = (__bf16)f.z; o[3] = (__bf16)f.w;
    *(bf16x4*)(Wob + e) = o;
  } else if (bid < 1792) {  // transposed casts: Wqt, Wkt, Wvt
    const int seg = (bid - 1024) >> 8;
    const int idx = (bid - 1024) & 255;
    const float* src = tp.p[seg];
    __bf16* dstw = seg == 0 ? Wqt : (seg == 1 ? Wkt : Wvt);
    const int r0 = (idx >> 4) * 64, c0 = (idx & 15) * 64;
#pragma unroll
    for (int e = 0; e < 16; ++e) {
      const int i = e * 256 + t;
      const int r = i >> 6, c = i & 63;
      tile[r][c] = (__bf16)src[(long)(r0 + r) * 1024 + (c0 + c)];
    }
    __syncthreads();
#pragma unroll
    for (int e = 0; e < 16; ++e) {
      const int i = e * 256 + t;
      const int r = i >> 6, c = i & 63;
      dstw[(long)(c0 + r) * 1024 + (r0 + c)] = tile[c][r];
    }
  } else if (bid < 2816) {  // bvo
    const int d = bid - 1792;
    const float* row = Wo + (long)d * 1024;
    float s = 0.f;
    for (int v = t; v < 1024; v += 256) s += bv[v] * row[v];
#pragma unroll
    for (int off = 32; off > 0; off >>= 1) s += __shfl_down(s, off, 64);
    if ((t & 63) == 0) wsum[t >> 6] = s;
    __syncthreads();
    if (t == 0) bvo[d] = wsum[0] + wsum[1] + wsum[2] + wsum[3];
  } else if (bid == 2816) {  // c = bq . bk
    float s = 0.f;
    for (int i = t; i < 1024; i += 256) s += bq[i] * bk[i];
#pragma unroll
    for (int off = 32; off > 0; off >>= 1) s += __shfl_down(s, off, 64);
    if ((t & 63) == 0) wsum[t >> 6] = s;
    __syncthreads();
    if (t == 0) *cscal = wsum[0] + wsum[1] + wsum[2] + wsum[3];
  } else {  // zero lsum
#pragma unroll
    for (int e = 0; e < 8; ++e)
      *(float4*)(lsum + (e * 256 + t) * 4) = float4{0.f, 0.f, 0.f, 0.f};
  }
}

// ---------------- gemmA: Mt(64) + Wvo(64) + m1(16) + m2(16) + x cast(8192) --
__global__ void __launch_bounds__(256, 3)
gemmA(const __bf16* __restrict__ Wkt, const __bf16* __restrict__ Wqt,
      const __bf16* __restrict__ Wob, const __bf16* __restrict__ Wvt,
      __bf16* __restrict__ Mt, __bf16* __restrict__ Wvo,
      const float* __restrict__ bk, const float* __restrict__ bq,
      float* __restrict__ m1f, float* __restrict__ m2f,
      const float* __restrict__ x, __bf16* __restrict__ xb) {
  const int id = blockIdx.x;
  const int t = threadIdx.x;

  if (id >= 160) {  // x cast
    const long i = ((long)(id - 160) * 256 + t) * 4;
    const float4 f = *(const float4*)(x + i);
    bf16x4 o;
    o[0] = (__bf16)f.x; o[1] = (__bf16)f.y; o[2] = (__bf16)f.z; o[3] = (__bf16)f.w;
    *(bf16x4*)(xb + i) = o;
    return;
  }
  if (id >= 128) {  // m1[d] = Wqt[d,:].bk  /  m2[e] = Wkt[e,:].bq
    const int q = (id - 128) & 15;
    const bool isM2 = (id - 128) >= 16;
    const __bf16* Wt = isM2 ? Wkt : Wqt;
    const float* bvec = isM2 ? bq : bk;
    float* dst = isM2 ? m2f : m1f;
    const int lane = t & 63, wave = t >> 6, qd = lane >> 4, l16 = lane & 15;
#pragma unroll
    for (int rr = 0; rr < 4; ++rr) {
      const int row = q * 64 + (wave * 4 + qd) * 4 + rr;
      const __bf16* wr = Wt + (long)row * 1024 + l16 * 64;
      const float* bp = bvec + l16 * 64;
      float s = 0.f;
#pragma unroll
      for (int jj = 0; jj < 8; ++jj) {
        bf16x8 wv = *(const bf16x8*)(wr + jj * 8);
#pragma unroll
        for (int e = 0; e < 8; ++e) s += (float)wv[e] * bp[jj * 8 + e];
      }
      s += __shfl_xor(s, 1, 64);
      s += __shfl_xor(s, 2, 64);
      s += __shfl_xor(s, 4, 64);
      s += __shfl_xor(s, 8, 64);
      if (l16 == 0) dst[row] = s;
    }
    return;
  }

  const __bf16 *pA, *pB;
  __bf16* dst;
  int mb, nb;
  if (id < 64) {
    mb = id >> 3; nb = id & 7;
    pA = Wkt; pB = Wqt; dst = Mt;
  } else {
    const int w = id - 64;
    mb = w >> 3; nb = w & 7;
    pA = Wob; pB = Wvt; dst = Wvo;
  }

  floatx4 acc[4][4] = {};
  gemm_core(pA, pB, 1024, 0, 32, mb, nb, acc);

  const int lane = t & 63, wave = t >> 6;
  const int rb = (wave >> 1) * 64 + (lane >> 4) * 4;
  const int cb = (wave & 1) * 64 + (lane & 15);
#pragma unroll
  for (int j4 = 0; j4 < 4; ++j4) {
    const int gc = nb * 128 + cb + j4 * 16;
#pragma unroll
    for (int i = 0; i < 4; ++i) {
      const int gr = mb * BM + rb + i * 16;
#pragma unroll
      for (int r = 0; r < 4; ++r)
        dst[(long)(gr + r) * 1024 + gc] = (__bf16)acc[i][j4][r];
    }
  }
}

// ---------------- big1: y2(128) + Ut(128) @256^2 + u GEMV(128) --------------
__global__ void __launch_bounds__(512, 2)
big1(const __bf16* __restrict__ xb, const __bf16* __restrict__ Mt,
     const __bf16* __restrict__ Wvo, const float* __restrict__ m2f,
     const float* __restrict__ bvo, __bf16* __restrict__ y2,
     __bf16* __restrict__ Ut, const float* __restrict__ m1f,
     const float* __restrict__ cscal, float* __restrict__ uvec,
     int S, int D) {
  const int id = blockIdx.x;
  const int t = threadIdx.x;

  if (id >= 256) {  // u rows: 128 blocks x 64 rows, 8 threads/row
    const int k = id - 256;
    const int row = k * 64 + (t >> 3);
    const int l8 = t & 7;
    const float c = *cscal;
    const __bf16* xr = xb + (long)row * 1024 + l8 * 128;
    const float* mp = m1f + l8 * 128;
    float s = 0.f;
#pragma unroll
    for (int jj = 0; jj < 16; ++jj) {
      bf16x8 xv = *(const bf16x8*)(xr + jj * 8);
#pragma unroll
      for (int e = 0; e < 8; ++e) s += (float)xv[e] * mp[jj * 8 + e];
    }
    s += __shfl_xor(s, 1, 64);
    s += __shfl_xor(s, 2, 64);
    s += __shfl_xor(s, 4, 64);
    if (l8 == 0) uvec[row] = s + c;
    return;
  }

  const bool isY2 = id < 128;
  const int w = isY2 ? id : id - 128;
  const int mb = w >> 2;   // 0..31 (8192 rows / 256)
  const int nb = w & 3;    // 0..3  (1024 cols / 256)
  const __bf16* pB = isY2 ? Mt : Wvo;

  floatx4 acc[8][4] = {};
  gemm_core256(xb, pB, 1024, 0, 32, mb, nb, acc);

  const int lane = t & 63, wave = t >> 6;
  const int quad = lane >> 4, l16 = lane & 15;
  const int wm = wave >> 2, wn = wave & 3;

  if (isY2) {
#pragma unroll
    for (int j = 0; j < 4; ++j) {
      const int gc = nb * 256 + wn * 64 + j * 16 + l16;
      const float bvv = m2f[gc];
#pragma unroll
      for (int i = 0; i < 8; ++i) {
        const int gr = mb * 256 + wm * 128 + i * 16 + quad * 4;
#pragma unroll
        for (int r = 0; r < 4; ++r)
          y2[(long)(gr + r) * 1024 + gc] = (__bf16)(acc[i][j][r] + bvv);
      }
    }
  } else {
    // Ut[bb][gc][sr] = U[bb][sr][gc]; 256-row tile lies in one batch
    const int bb = (mb * 256) / S;
    const int s0 = mb * 256 - bb * S;
#pragma unroll
    for (int j = 0; j < 4; ++j) {
      const int gc = nb * 256 + wn * 64 + j * 16 + l16;
      const float bv = bvo[gc];
#pragma unroll
      for (int i = 0; i < 8; ++i) {
        const int sr = s0 + wm * 128 + i * 16 + quad * 4;
        bf16x4 o;
#pragma unroll
        for (int r = 0; r < 4; ++r) o[r] = (__bf16)(acc[i][j][r] + bv);
        *(bf16x4*)&Ut[((long)bb * D + gc) * S + sr] = o;
      }
    }
  }
}

// ---------------- scoresK: P = exp(|y2.x^T+u|/32) causal + rowsums ----------
__global__ void __launch_bounds__(256, 3)
scoresK(const __bf16* __restrict__ xb, const __bf16* __restrict__ y2,
        const float* __restrict__ uvec, __bf16* __restrict__ P,
        float* __restrict__ lsum, int S, int KD) {
  const int sid = blockIdx.x;
  const int xcd = sid & 7;
  const int r = sid >> 3;       // 0..67
  const int b = r / 17;
  const int ci = r - b * 17;    // 0..16
  const int n1 = xcd + 1;
  const int mb = (ci < n1) ? xcd : (15 - xcd);
  const int nb = (ci < n1) ? ci : (ci - n1);
  const __bf16* pA = y2 + (long)b * S * KD;
  const __bf16* pB = xb + (long)b * S * KD;

  floatx4 acc[4][4] = {};
  gemm_core(pA, pB, KD, 0, KD / 32, mb, nb, acc);

  const int t = threadIdx.x;
  const int lane = t & 63, wave = t >> 6;
  const int l16 = lane & 15;
  const int rb = (wave >> 1) * 64 + (lane >> 4) * 4;
  const int cb = (wave & 1) * 64 + l16;

  __bf16* C = P + (long)b * S * S;
  float* lrow = lsum + (long)b * S;
  const float sc = 0.03125f;  // 1/sqrt(1024)
#pragma unroll
  for (int i = 0; i < 4; ++i) {
#pragma unroll
    for (int r4 = 0; r4 < 4; ++r4) {
      const int row = mb * BM + rb + i * 16 + r4;
      const float urow = uvec[(long)b * S + row];
      float psum = 0.f;
#pragma unroll
      for (int j4 = 0; j4 < 4; ++j4) {
        const int col = nb * 128 + cb + j4 * 16;
        const float p =
            (col <= row) ? __expf(fabsf(acc[i][j4][r4] + urow) * sc) : 0.f;
        psum += p;
        C[(long)row * S + col] = (__bf16)p;
      }
      psum += __shfl_xor(psum, 1, 64);
      psum += __shfl_xor(psum, 2, 64);
      psum += __shfl_xor(psum, 4, 64);
      psum += __shfl_xor(psum, 8, 64);
      if (l16 == 0) atomicAdd(&lrow[row], psum);
    }
  }
}

// ---------------- pvo: out = (P @ U)/l + bo, fp32 ---------------------------
__global__ void __launch_bounds__(256, 3)
gemm_pvo(const __bf16* __restrict__ P, const __bf16* __restrict__ Ut,
         const float* __restrict__ lsum, const float* __restrict__ bo,
         float* __restrict__ out, int S, int D) {
  const int id = blockIdx.x;
  const int xcd = id & 7;
  const int j = id >> 3;
  const int half = j >> 5;
  const int idx = j & 31;
  const int b = idx >> 3;
  const int nb = idx & 7;
  const int mb = half ? xcd : (15 - xcd);

  floatx4 acc[4][4] = {};
  gemm_core(P + (long)b * S * S, Ut + (long)b * D * S, S, 0, 4 * (mb + 1), mb,
            nb, acc);

  const int t = threadIdx.x;
  const int lane = t & 63, wave = t >> 6;
  const int rb = (wave >> 1) * 64 + (lane >> 4) * 4;
  const int cb = (wave & 1) * 64 + (lane & 15);
  const float* lrow = lsum + (long)b * S;

#pragma unroll
  for (int i = 0; i < 4; ++i) {
#pragma unroll
    for (int r = 0; r < 4; ++r) {
      const int row = mb * BM + rb + i * 16 + r;
      const float inv = 1.f / lrow[row];
#pragma unroll
      for (int j4 = 0; j4 < 4; ++j4) {
        const int col = nb * 128 + cb + j4 * 16;
        out[((long)b * S + row) * D + col] = acc[i][j4][r] * inv + bo[col];
      }
    }
  }
}

extern "C" void kernel_launch(void* const* d_in, const int* in_sizes, int n_in,
                              void* d_out, int out_size, void* d_ws, size_t ws_size,
                              hipStream_t stream) {
  const float* x = (const float*)d_in[0];
  const float* Wq = (const float*)d_in[1];
  const float* bq = (const float*)d_in[2];
  const float* Wk = (const float*)d_in[3];
  const float* bk = (const float*)d_in[4];
  const float* Wv = (const float*)d_in[5];
  const float* bv = (const float*)d_in[6];
  const float* Wo = (const float*)d_in[7];
  const float* bo = (const float*)d_in[8];
  float* out = (float*)d_out;

  constexpr int B = 4, S = 2048, D = 1024, KD = 1024;
  constexpr long MB_ = 1024 * 1024;

  char* w = (char*)d_ws;
  __bf16* xb  = (__bf16*)(w);              // 16 MB
  __bf16* y2  = (__bf16*)(w + 16 * MB_);   // 16 MB
  __bf16* Ut  = (__bf16*)(w + 32 * MB_);   // 16 MB
  __bf16* P   = (__bf16*)(w + 48 * MB_);   // 32 MB
  __bf16* Wob = (__bf16*)(w + 80 * MB_);   // 2 MB
  __bf16* Wqt = (__bf16*)(w + 82 * MB_);   // 2 MB
  __bf16* Wkt = (__bf16*)(w + 84 * MB_);   // 2 MB
  __bf16* Wvt = (__bf16*)(w + 86 * MB_);   // 2 MB
  __bf16* Mt  = (__bf16*)(w + 88 * MB_);   // 2 MB
  __bf16* Wvo = (__bf16*)(w + 90 * MB_);   // 2 MB
  float* lsum  = (float*)(w + 92 * MB_);             // 32 KB
  float* uvec  = (float*)(w + 92 * MB_ + 32768);     // 32 KB
  float* bvo   = (float*)(w + 92 * MB_ + 65536);     // 4 KB
  float* m2f   = (float*)(w + 92 * MB_ + 69632);     // 4 KB
  float* m1f   = (float*)(w + 92 * MB_ + 73728);     // 4 KB
  float* cscal = (float*)(w + 92 * MB_ + 77824);     // 4 B

  Ptr3 tp{{Wq, Wk, Wv}};
  prep2<<<2818, 256, 0, stream>>>(Wo, tp, bv, bq, bk, Wob, Wqt, Wkt, Wvt,
                                  bvo, cscal, lsum);

  gemmA<<<8352, 256, 0, stream>>>(Wkt, Wqt, Wob, Wvt, Mt, Wvo, bk, bq,
                                  m1f, m2f, x, xb);

  big1<<<384, 512, 0, stream>>>(xb, Mt, Wvo, m2f, bvo, y2, Ut, m1f, cscal,
                                uvec, S, D);

  scoresK<<<544, 256, 0, stream>>>(xb, y2, uvec, P, lsum, S, KD);

  gemm_pvo<<<512, 256, 0, stream>>>(P, Ut, lsum, bo, out, S, D);
}